// Round 2
// baseline (327.961 us; speedup 1.0000x reference)
//
#include <hip/hip_runtime.h>

#define GM_EPS 1e-8f

__global__ __launch_bounds__(256) void gaussian_merge_kernel(
    const float* __restrict__ loc1,
    const float* __restrict__ scale1,
    const float* __restrict__ rot1,
    const float* __restrict__ loc2,
    const float* __restrict__ scale2,
    const float* __restrict__ rot2,
    float* __restrict__ out_loc,   // [n,3]
    float* __restrict__ out_cov,   // [n,3,3]
    int n)
{
    int i = blockIdx.x * blockDim.x + threadIdx.x;
    if (i >= n) return;

    const long ib3 = (long)i * 3;
    const long ib9 = (long)i * 9;

    // ---- loads (per-thread contiguous chunks) ----
    float l1[3], l2[3], s1[3], s2[3];
#pragma unroll
    for (int k = 0; k < 3; ++k) {
        l1[k] = loc1[ib3 + k];
        l2[k] = loc2[ib3 + k];
        s1[k] = scale1[ib3 + k];
        s2[k] = scale2[ib3 + k];
    }
    float R1[9], R2[9];
#pragma unroll
    for (int k = 0; k < 9; ++k) {
        R1[k] = rot1[ib9 + k];
        R2[k] = rot2[ib9 + k];
    }

    // ---- c1 = R1 diag(s1) R1^T ; S = c1 + c2 + eps*I ----
    float c1[3][3], S[3][3];
#pragma unroll
    for (int a = 0; a < 3; ++a) {
#pragma unroll
        for (int b = 0; b < 3; ++b) {
            float v1 = 0.f, v2 = 0.f;
#pragma unroll
            for (int k = 0; k < 3; ++k) {
                v1 = fmaf(R1[a * 3 + k] * s1[k], R1[b * 3 + k], v1);
                v2 = fmaf(R2[a * 3 + k] * s2[k], R2[b * 3 + k], v2);
            }
            c1[a][b] = v1;
            S[a][b]  = v1 + v2 + (a == b ? GM_EPS : 0.f);
        }
    }

    // ---- Sinv = inv(S) via adjugate (S symmetric) ----
    const float m00 = S[0][0], m01 = S[0][1], m02 = S[0][2];
    const float m11 = S[1][1], m12 = S[1][2], m22 = S[2][2];
    const float A0 = m11 * m22 - m12 * m12;
    const float A1 = m02 * m12 - m01 * m22;
    const float A2 = m01 * m12 - m02 * m11;
    const float det = m00 * A0 + m01 * A1 + m02 * A2;
    const float invdet = 1.0f / det;

    float Sinv[3][3];
    Sinv[0][0] = A0 * invdet;
    Sinv[0][1] = A1 * invdet;
    Sinv[0][2] = A2 * invdet;
    Sinv[1][1] = (m00 * m22 - m02 * m02) * invdet;
    Sinv[1][2] = (m01 * m02 - m00 * m12) * invdet;
    Sinv[2][2] = (m00 * m11 - m01 * m01) * invdet;
    Sinv[1][0] = Sinv[0][1];
    Sinv[2][0] = Sinv[0][2];
    Sinv[2][1] = Sinv[1][2];

    // ---- K = c1 @ Sinv ----
    float K[3][3];
#pragma unroll
    for (int a = 0; a < 3; ++a) {
#pragma unroll
        for (int b = 0; b < 3; ++b) {
            float v = 0.f;
#pragma unroll
            for (int k = 0; k < 3; ++k)
                v = fmaf(c1[a][k], Sinv[k][b], v);
            K[a][b] = v;
        }
    }

    // ---- loc_new = loc1 + K @ (loc2 - loc1) ----
    float d0 = l2[0] - l1[0], d1 = l2[1] - l1[1], d2 = l2[2] - l1[2];
#pragma unroll
    for (int a = 0; a < 3; ++a) {
        float v = fmaf(K[a][0], d0, fmaf(K[a][1], d1, K[a][2] * d2));
        out_loc[ib3 + a] = l1[a] + v;
    }

    // ---- cov_new = c1 + K @ c1 ----
#pragma unroll
    for (int a = 0; a < 3; ++a) {
#pragma unroll
        for (int b = 0; b < 3; ++b) {
            float v = 0.f;
#pragma unroll
            for (int k = 0; k < 3; ++k)
                v = fmaf(K[a][k], c1[k][b], v);
            out_cov[ib9 + a * 3 + b] = c1[a][b] + v;
        }
    }
}

extern "C" void kernel_launch(void* const* d_in, const int* in_sizes, int n_in,
                              void* d_out, int out_size, void* d_ws, size_t ws_size,
                              hipStream_t stream) {
    const float* loc1   = (const float*)d_in[0];
    const float* scale1 = (const float*)d_in[1];
    const float* rot1   = (const float*)d_in[2];
    const float* loc2   = (const float*)d_in[3];
    const float* scale2 = (const float*)d_in[4];
    const float* rot2   = (const float*)d_in[5];
    // d_in[6], d_in[7] = cov1/cov2 placeholders: reference recomputes them.

    const int n = in_sizes[0] / 3;  // loc1 is [n,3]

    float* out     = (float*)d_out;
    float* out_loc = out;                    // [n,3]
    float* out_cov = out + (size_t)n * 3;    // [n,3,9... [n,3,3]

    const int block = 256;
    const int grid  = (n + block - 1) / block;
    gaussian_merge_kernel<<<grid, block, 0, stream>>>(
        loc1, scale1, rot1, loc2, scale2, rot2, out_loc, out_cov, n);
}